// Round 1
// baseline (201.082 us; speedup 1.0000x reference)
//
#include <hip/hip_runtime.h>

// VectorQuantizer: z [16,64,64,64] f32, emb [1024,64] f32
// out: quantized_st [16,64,64,64] f32 (= emb[argmin] scattered), then loss scalar.
// N = 65536 spatial vectors (dim 64), K = 1024 codes.
//
// argmin_k ||z-e_k||^2 == argmin_k (||e_k||^2 - 2 z.e_k)   (score s_k)
// ||z - e_best||^2 = ||z||^2 + s_best                      (for the loss)
// loss = (1 + 0.25) * mean((q - z)^2)

#define K_CODES 1024
#define DIM 64
#define N_TOTAL 65536
#define NCHUNK 4
#define CHUNK 256  // K_CODES / NCHUNK

// ws layout (float offsets)
#define OFF_ET     0        // eT[c][k]  : DIM*K_CODES = 65536
#define OFF_ENORM  65536    // ||e_k||^2 : 1024
#define OFF_ACCUM  66560    // loss accumulator : 1
#define OFF_ZSQ    66624    // ||z_n||^2 : 65536
#define OFF_PSCORE 132160   // partial best score [NCHUNK][N] : 262144
#define OFF_PIDX   394304   // partial best idx   [NCHUNK][N] : 262144 (int)
// total: 656448 floats = 2.63 MB

__global__ void vq_prep_transpose(const float* __restrict__ emb,
                                  float* __restrict__ eT) {
    int i = blockIdx.x * 256 + threadIdx.x;   // 65536 threads
    int c = i >> 10, k = i & 1023;
    eT[i] = emb[(k << 6) + c];
}

__global__ void vq_prep_enorm(const float* __restrict__ emb,
                              float* __restrict__ enorm,
                              float* __restrict__ accum) {
    int k = blockIdx.x;          // 1024 blocks x 64 threads (1 wave)
    int c = threadIdx.x;
    float v = emb[(k << 6) + c];
    float s = v * v;
    #pragma unroll
    for (int o = 32; o > 0; o >>= 1) s += __shfl_down(s, o);
    if (c == 0) enorm[k] = s;
    if (k == 0 && c == 0) accum[0] = 0.0f;   // zero loss accumulator each call
}

__global__ void vq_dist(const float* __restrict__ z,
                        const float* __restrict__ eT,
                        const float* __restrict__ enorm,
                        float* __restrict__ pscore,
                        int*   __restrict__ pidx,
                        float* __restrict__ zsq) {
    const int chunk = blockIdx.x >> 8;                       // 0..3
    const int n = ((blockIdx.x & 255) << 8) + threadIdx.x;   // 0..65535
    // z index for channel c: b*64*4096 + c*4096 + (h*64+w); n = b*4096 + hw
    const int base = ((n >> 12) << 18) + (n & 4095);

    float zr[DIM];
    #pragma unroll
    for (int c = 0; c < DIM; ++c) zr[c] = z[base + (c << 12)];

    if (chunk == 0) {
        float s = 0.0f;
        #pragma unroll
        for (int c = 0; c < DIM; ++c) s = fmaf(zr[c], zr[c], s);
        zsq[n] = s;
    }

    float best = 3.0e38f;
    int bidx = 0;
    const int k0beg = chunk << 8;
    for (int k0 = k0beg; k0 < k0beg + CHUNK; k0 += 8) {
        float acc[8];
        #pragma unroll
        for (int j = 0; j < 8; ++j) acc[j] = 0.0f;
        #pragma unroll
        for (int c = 0; c < DIM; ++c) {
            const float zc = zr[c];
            #pragma unroll
            for (int j = 0; j < 8; ++j)
                acc[j] = fmaf(zc, eT[(c << 10) + k0 + j], acc[j]);
        }
        #pragma unroll
        for (int j = 0; j < 8; ++j) {
            float s = fmaf(-2.0f, acc[j], enorm[k0 + j]);
            if (s < best) { best = s; bidx = k0 + j; }  // strict < => first-min
        }
    }
    pscore[chunk * N_TOTAL + n] = best;
    pidx[chunk * N_TOTAL + n] = bidx;
}

__global__ void vq_finalize(const float* __restrict__ emb,
                            const float* __restrict__ pscore,
                            const int* __restrict__ pidx,
                            const float* __restrict__ zsq,
                            float* __restrict__ out,
                            float* __restrict__ accum) {
    const int n = blockIdx.x * 256 + threadIdx.x;
    float best = pscore[n];
    int bidx = pidx[n];
    #pragma unroll
    for (int ch = 1; ch < NCHUNK; ++ch) {   // ascending chunk + strict < => first-min
        float s = pscore[ch * N_TOTAL + n];
        int i2 = pidx[ch * N_TOTAL + n];
        if (s < best) { best = s; bidx = i2; }
    }
    const int base = ((n >> 12) << 18) + (n & 4095);
    const float4* erow = (const float4*)(emb + (bidx << 6));
    #pragma unroll
    for (int c4 = 0; c4 < 16; ++c4) {
        float4 q = erow[c4];
        out[base + ((c4 * 4 + 0) << 12)] = q.x;
        out[base + ((c4 * 4 + 1) << 12)] = q.y;
        out[base + ((c4 * 4 + 2) << 12)] = q.z;
        out[base + ((c4 * 4 + 3) << 12)] = q.w;
    }
    // ||z-q||^2 = ||z||^2 + best_score
    float local = zsq[n] + best;
    #pragma unroll
    for (int o = 32; o > 0; o >>= 1) local += __shfl_down(local, o);
    __shared__ float red[4];
    const int lane = threadIdx.x & 63, wid = threadIdx.x >> 6;
    if (lane == 0) red[wid] = local;
    __syncthreads();
    if (threadIdx.x == 0)
        atomicAdd(accum, red[0] + red[1] + red[2] + red[3]);
}

__global__ void vq_loss(const float* __restrict__ accum,
                        float* __restrict__ out_loss) {
    // loss = q_latent + 0.25*e_latent = 1.25 * mean((q-z)^2) over 4194304 elems
    out_loss[0] = 1.25f * accum[0] * (1.0f / 4194304.0f);
}

extern "C" void kernel_launch(void* const* d_in, const int* in_sizes, int n_in,
                              void* d_out, int out_size, void* d_ws, size_t ws_size,
                              hipStream_t stream) {
    const float* z   = (const float*)d_in[0];
    const float* emb = (const float*)d_in[1];
    float* out = (float*)d_out;
    float* ws  = (float*)d_ws;

    float* eT     = ws + OFF_ET;
    float* enorm  = ws + OFF_ENORM;
    float* accum  = ws + OFF_ACCUM;
    float* zsq    = ws + OFF_ZSQ;
    float* pscore = ws + OFF_PSCORE;
    int*   pidx   = (int*)(ws + OFF_PIDX);

    hipLaunchKernelGGL(vq_prep_transpose, dim3(256), dim3(256), 0, stream, emb, eT);
    hipLaunchKernelGGL(vq_prep_enorm, dim3(1024), dim3(64), 0, stream, emb, enorm, accum);
    hipLaunchKernelGGL(vq_dist, dim3(NCHUNK * 256), dim3(256), 0, stream,
                       z, eT, enorm, pscore, pidx, zsq);
    hipLaunchKernelGGL(vq_finalize, dim3(256), dim3(256), 0, stream,
                       emb, pscore, pidx, zsq, out, accum);
    hipLaunchKernelGGL(vq_loss, dim3(1), dim3(1), 0, stream, accum, out + 4194304);
}

// Round 2
// 33.553 us; speedup vs baseline: 5.9930x; 5.9930x over previous
//
#include <hip/hip_runtime.h>

// VQ via bf16 MFMA: score s'_k = (enorm_k + 4) - 2 z.e_k  (C-init carries enorm+4)
// argmin over uint-ordered truncated keys: (bits(s')&~1023) | code_idx
// z: [16,64,64,64] f32 (channel-major), emb: [1024,64] f32.
// out: quantized [4194304] f32 + loss [1].

typedef short short4v __attribute__((ext_vector_type(4)));
typedef short short8v __attribute__((ext_vector_type(8)));
typedef float f32x4   __attribute__((ext_vector_type(4)));

#define N_TOTAL 65536

// ws byte offsets
#define OFF_EPACK 0        // 65536 bf16 = 131072 B  (-2*e in MFMA B-frag layout)
#define OFF_ENORM 131072   // 1024 f32 = 4096 B      (||e||^2 + 4)
#define OFF_ACCUM 135168   // 1 f32 (pad to 128)
#define OFF_PIDX  135296   // 65536 int = 262144 B

__device__ __forceinline__ unsigned short bf16r(float f) {
    unsigned u = __float_as_uint(f);
    return (unsigned short)((u + 0x7FFFu + ((u >> 16) & 1u)) >> 16);
}
__device__ __forceinline__ unsigned umin2(unsigned a, unsigned b) { return a < b ? a : b; }

// 1024 blocks x 64 threads: enormS4 + ePack (frag layout: ((t*2+s)*64 + lane)*8 + i,
// where code = t*16 + (lane&15), k = s*32 + (lane>>4)*8 + i)
__global__ void vq_prep(const float* __restrict__ emb,
                        short* __restrict__ ePack,
                        float* __restrict__ enormS4,
                        float* __restrict__ accum) {
    const int code = blockIdx.x;
    const int k = threadIdx.x;
    const float v = emb[(code << 6) + k];
    float s = v * v;
    #pragma unroll
    for (int o = 32; o > 0; o >>= 1) s += __shfl_down(s, o);
    if (k == 0) enormS4[code] = s + 4.0f;
    if (code == 0 && k == 0) accum[0] = 0.0f;
    const int t   = code >> 4;
    const int s32 = k >> 5;
    const int l   = (((k >> 3) & 3) << 4) | (code & 15);
    const int i   = k & 7;
    ePack[(((t * 2 + s32) * 64) + l) * 8 + i] = (short)bf16r(-2.0f * v);
}

// 512 blocks x 256 threads (4 waves). Block: 128 rows; wave w: codes [w*256, w*256+256).
__global__ __launch_bounds__(256, 2)
void vq_main(const float* __restrict__ z,
             const short* __restrict__ ePack,
             const float* __restrict__ enormS4,
             int* __restrict__ pidx,
             float* __restrict__ accum) {
    __shared__ short zt[128][68];          // bf16 z-tile, stride 68 (8B-aligned rows, low conflict)
    __shared__ float zsqp[2][128];
    __shared__ unsigned kbuf[4][128];
    __shared__ float red[4];

    const int tid  = threadIdx.x;
    const int lane = tid & 63;
    const int w    = tid >> 6;
    const int col  = lane & 15;
    const int row0 = blockIdx.x << 7;

    // B-frags (all 256 codes of this wave) + enorm into registers. L1/L2-resident.
    short8v b0[16], b1[16];
    float en[16];
    {
        const short* ep = ePack + ((w << 11) + lane) * 8;   // (w*32*64 + lane)*8
        #pragma unroll
        for (int j = 0; j < 16; ++j) {
            b0[j] = *(const short8v*)(ep + (j * 2    ) * 512);
            b1[j] = *(const short8v*)(ep + (j * 2 + 1) * 512);
            en[j] = enormS4[(w << 8) + (j << 4) + col];
        }
    }

    // Stage z: thread -> (row r = tid&127, c-half h = tid>>7). fp32 zsq on the fly.
    {
        const int r = tid & 127;
        const int h = tid >> 7;
        const int n = row0 + r;
        const int base = ((n >> 12) << 18) + (n & 4095);   // b*64*4096 + hw
        float ss = 0.0f;
        #pragma unroll
        for (int j = 0; j < 16; ++j) {
            const int c = (h << 5) + (j << 1);
            const float f0 = z[base + (c << 12)];
            const float f1 = z[base + ((c + 1) << 12)];
            ss = fmaf(f1, f1, fmaf(f0, f0, ss));
            const unsigned p = (unsigned)bf16r(f0) | ((unsigned)bf16r(f1) << 16);
            *(unsigned*)&zt[r][c] = p;
        }
        zsqp[h][r] = ss;
    }
    __syncthreads();

    const unsigned MASK = 0xFFFFFC00u;
    const int idxbase = (w << 8) + col;
    const int k0 = (lane >> 4) << 3;

    for (int ch = 0; ch < 8; ++ch) {
        const int r = (ch << 4) + col;                      // A-row = lane&15
        const short4v a0lo = *(const short4v*)&zt[r][k0];
        const short4v a0hi = *(const short4v*)&zt[r][k0 + 4];
        const short4v a1lo = *(const short4v*)&zt[r][k0 + 32];
        const short4v a1hi = *(const short4v*)&zt[r][k0 + 36];
        const short8v a0 = __builtin_shufflevector(a0lo, a0hi, 0,1,2,3,4,5,6,7);
        const short8v a1 = __builtin_shufflevector(a1lo, a1hi, 0,1,2,3,4,5,6,7);
        unsigned pb0 = 0xFFFFFFFFu, pb1 = 0xFFFFFFFFu;
        unsigned pb2 = 0xFFFFFFFFu, pb3 = 0xFFFFFFFFu;
        #pragma unroll
        for (int j = 0; j < 16; ++j) {
            f32x4 c = {en[j], en[j], en[j], en[j]};         // C-init = enorm + 4
            c = __builtin_amdgcn_mfma_f32_16x16x32_bf16(a0, b0[j], c, 0, 0, 0);
            c = __builtin_amdgcn_mfma_f32_16x16x32_bf16(a1, b1[j], c, 0, 0, 0);
            const unsigned idx = (unsigned)(idxbase + (j << 4));
            pb0 = umin2(pb0, (__float_as_uint(c[0]) & MASK) | idx);
            pb1 = umin2(pb1, (__float_as_uint(c[1]) & MASK) | idx);
            pb2 = umin2(pb2, (__float_as_uint(c[2]) & MASK) | idx);
            pb3 = umin2(pb3, (__float_as_uint(c[3]) & MASK) | idx);
        }
        #pragma unroll
        for (int m = 1; m < 16; m <<= 1) {                  // reduce over 16 cols
            pb0 = umin2(pb0, (unsigned)__shfl_xor((int)pb0, m));
            pb1 = umin2(pb1, (unsigned)__shfl_xor((int)pb1, m));
            pb2 = umin2(pb2, (unsigned)__shfl_xor((int)pb2, m));
            pb3 = umin2(pb3, (unsigned)__shfl_xor((int)pb3, m));
        }
        if (col == 0) {                                     // rows (lane>>4)*4 + r
            const int rb = (ch << 4) + ((lane >> 4) << 2);
            kbuf[w][rb + 0] = pb0;
            kbuf[w][rb + 1] = pb1;
            kbuf[w][rb + 2] = pb2;
            kbuf[w][rb + 3] = pb3;
        }
    }
    __syncthreads();

    // cross-wave argmin + loss partial
    float d = 0.0f;
    if (tid < 128) {
        const unsigned kk = umin2(umin2(kbuf[0][tid], kbuf[1][tid]),
                                  umin2(kbuf[2][tid], kbuf[3][tid]));
        pidx[row0 + tid] = (int)(kk & 1023u);
        d = __uint_as_float(kk & MASK) - 4.0f + zsqp[0][tid] + zsqp[1][tid];
    }
    #pragma unroll
    for (int m = 1; m < 64; m <<= 1) d += __shfl_xor(d, m);
    if (lane == 0) red[w] = d;
    __syncthreads();
    if (tid == 0) atomicAdd(accum, red[0] + red[1] + red[2] + red[3]);
}

// gather + scatter to channel-major output
__global__ void vq_out(const float* __restrict__ emb,
                       const int* __restrict__ pidx,
                       float* __restrict__ out) {
    const int n = blockIdx.x * 256 + threadIdx.x;
    const int bidx = pidx[n];
    const int base = ((n >> 12) << 18) + (n & 4095);
    const float4* erow = (const float4*)(emb + (bidx << 6));
    #pragma unroll
    for (int c4 = 0; c4 < 16; ++c4) {
        const float4 q = erow[c4];
        out[base + ((c4 * 4 + 0) << 12)] = q.x;
        out[base + ((c4 * 4 + 1) << 12)] = q.y;
        out[base + ((c4 * 4 + 2) << 12)] = q.z;
        out[base + ((c4 * 4 + 3) << 12)] = q.w;
    }
}

__global__ void vq_loss(const float* __restrict__ accum,
                        float* __restrict__ out_loss) {
    out_loss[0] = 1.25f * accum[0] * (1.0f / 4194304.0f);
}

extern "C" void kernel_launch(void* const* d_in, const int* in_sizes, int n_in,
                              void* d_out, int out_size, void* d_ws, size_t ws_size,
                              hipStream_t stream) {
    const float* z   = (const float*)d_in[0];
    const float* emb = (const float*)d_in[1];
    float* out = (float*)d_out;
    char*  ws  = (char*)d_ws;

    short* ePack   = (short*)(ws + OFF_EPACK);
    float* enormS4 = (float*)(ws + OFF_ENORM);
    float* accum   = (float*)(ws + OFF_ACCUM);
    int*   pidx    = (int*)  (ws + OFF_PIDX);

    hipLaunchKernelGGL(vq_prep, dim3(1024), dim3(64), 0, stream, emb, ePack, enormS4, accum);
    hipLaunchKernelGGL(vq_main, dim3(512), dim3(256), 0, stream, z, ePack, enormS4, pidx, accum);
    hipLaunchKernelGGL(vq_out,  dim3(256), dim3(256), 0, stream, emb, pidx, out);
    hipLaunchKernelGGL(vq_loss, dim3(1), dim3(1), 0, stream, accum, out + 4194304);
}

// Round 3
// 33.520 us; speedup vs baseline: 5.9988x; 1.0010x over previous
//
#include <hip/hip_runtime.h>
#include <hip/hip_bf16.h>

// Fully-fused VQ: score s'_k = (||e_k||^2 + 4) - 2 z.e_k  via bf16 MFMA
// (C-operand pre-initialized with enorm+4; all-positive scores ~4 so uint
// ordering == float ordering). Argmin via truncated-key trick:
//   key = (bits(s') & 0xFFFFFC00) | code_idx;  min over uint.
// z: [16,64,64,64] f32 channel-major; emb: [1024,64] f32.
// out: quantized [4194304] f32 (emb[argmin] scattered back) + loss [1].
// Kernel 1 (512 blocks x 256 thr): B-frags from emb in-reg, z->LDS bf16,
//   MFMA argmin, gather/scatter output, per-block loss partial -> pblk.
// Kernel 2: reduce pblk[512] -> loss. No atomics anywhere (deterministic).

typedef short short4v __attribute__((ext_vector_type(4)));
typedef short short8v __attribute__((ext_vector_type(8)));
typedef float f32x4   __attribute__((ext_vector_type(4)));

__device__ __forceinline__ unsigned pk2(float a, float b) {
    __hip_bfloat162 h = __float22bfloat162_rn(make_float2(a, b));
    return *reinterpret_cast<unsigned*>(&h);
}
__device__ __forceinline__ unsigned umin2(unsigned a, unsigned b) { return a < b ? a : b; }

__global__ __launch_bounds__(256, 2)
void vq_fused(const float* __restrict__ z,
              const float* __restrict__ emb,
              float* __restrict__ out,
              float* __restrict__ pblk) {
    __shared__ short zt[128][68];          // bf16 z-tile (row stride 68 shorts, 8B-aligned)
    __shared__ float zsqp[2][128];
    __shared__ unsigned kbuf[4][128];
    __shared__ float red[4];
    __shared__ int bsel[128];

    const int tid  = threadIdx.x;
    const int lane = tid & 63;
    const int w    = tid >> 6;             // wave: owns codes [w*256, w*256+256)
    const int col  = lane & 15;
    const int kg   = lane >> 4;            // 0..3
    const int row0 = blockIdx.x << 7;

    // ---- B-fragments + enorm directly from emb (identical layout to MFMA B) ----
    short8v b0[16], b1[16];
    float en4[16];
    {
        const float4* embv = (const float4*)emb;
        #pragma unroll
        for (int j = 0; j < 16; ++j) {
            const int code = (w << 8) + (j << 4) + col;
            const int rb = (code << 4) + (kg << 1);
            const float4 x0 = embv[rb];         // k = kg*8 .. +3
            const float4 x1 = embv[rb + 1];     // k = kg*8+4 .. +7
            const float4 x2 = embv[rb + 8];     // k = 32+kg*8 ..
            const float4 x3 = embv[rb + 9];
            float ss;
            ss = x0.x * x0.x;
            ss = fmaf(x0.y, x0.y, ss); ss = fmaf(x0.z, x0.z, ss); ss = fmaf(x0.w, x0.w, ss);
            ss = fmaf(x1.x, x1.x, ss); ss = fmaf(x1.y, x1.y, ss); ss = fmaf(x1.z, x1.z, ss);
            ss = fmaf(x1.w, x1.w, ss);
            ss = fmaf(x2.x, x2.x, ss); ss = fmaf(x2.y, x2.y, ss); ss = fmaf(x2.z, x2.z, ss);
            ss = fmaf(x2.w, x2.w, ss);
            ss = fmaf(x3.x, x3.x, ss); ss = fmaf(x3.y, x3.y, ss); ss = fmaf(x3.z, x3.z, ss);
            ss = fmaf(x3.w, x3.w, ss);
            ss += __shfl_xor(ss, 16);           // sum across the 4 kg groups (same code)
            ss += __shfl_xor(ss, 32);
            en4[j] = ss + 4.0f;
            union { short8v v; unsigned u[4]; } t;
            t.u[0] = pk2(-2.0f * x0.x, -2.0f * x0.y);
            t.u[1] = pk2(-2.0f * x0.z, -2.0f * x0.w);
            t.u[2] = pk2(-2.0f * x1.x, -2.0f * x1.y);
            t.u[3] = pk2(-2.0f * x1.z, -2.0f * x1.w);
            b0[j] = t.v;
            t.u[0] = pk2(-2.0f * x2.x, -2.0f * x2.y);
            t.u[1] = pk2(-2.0f * x2.z, -2.0f * x2.w);
            t.u[2] = pk2(-2.0f * x3.x, -2.0f * x3.y);
            t.u[3] = pk2(-2.0f * x3.z, -2.0f * x3.w);
            b1[j] = t.v;
        }
    }

    // ---- Stage z tile to LDS as bf16; fp32 zsq on the fly ----
    {
        const int r = tid & 127;
        const int h = tid >> 7;
        const int n = row0 + r;
        const int base = ((n >> 12) << 18) + (n & 4095);   // b*64*4096 + hw
        float ssz = 0.0f;
        #pragma unroll
        for (int j = 0; j < 16; ++j) {
            const int c = (h << 5) + (j << 1);
            const float f0 = z[base + (c << 12)];
            const float f1 = z[base + ((c + 1) << 12)];
            ssz = fmaf(f1, f1, fmaf(f0, f0, ssz));
            *(unsigned*)&zt[r][c] = pk2(f0, f1);
        }
        zsqp[h][r] = ssz;
    }
    __syncthreads();

    // ---- MFMA + truncated-key argmin ----
    const unsigned MASK = 0xFFFFFC00u;
    const int idxbase = (w << 8) + col;
    const int k0 = kg << 3;

    for (int ch = 0; ch < 8; ++ch) {
        const int r = (ch << 4) + col;                      // A-row = lane&15
        const short4v a0lo = *(const short4v*)&zt[r][k0];
        const short4v a0hi = *(const short4v*)&zt[r][k0 + 4];
        const short4v a1lo = *(const short4v*)&zt[r][k0 + 32];
        const short4v a1hi = *(const short4v*)&zt[r][k0 + 36];
        const short8v a0 = __builtin_shufflevector(a0lo, a0hi, 0,1,2,3,4,5,6,7);
        const short8v a1 = __builtin_shufflevector(a1lo, a1hi, 0,1,2,3,4,5,6,7);
        unsigned pb0 = 0xFFFFFFFFu, pb1 = 0xFFFFFFFFu;
        unsigned pb2 = 0xFFFFFFFFu, pb3 = 0xFFFFFFFFu;
        #pragma unroll
        for (int j = 0; j < 16; ++j) {
            f32x4 c = {en4[j], en4[j], en4[j], en4[j]};     // C-init = enorm + 4
            c = __builtin_amdgcn_mfma_f32_16x16x32_bf16(a0, b0[j], c, 0, 0, 0);
            c = __builtin_amdgcn_mfma_f32_16x16x32_bf16(a1, b1[j], c, 0, 0, 0);
            const unsigned idx = (unsigned)(idxbase + (j << 4));
            pb0 = umin2(pb0, (__float_as_uint(c[0]) & MASK) | idx);
            pb1 = umin2(pb1, (__float_as_uint(c[1]) & MASK) | idx);
            pb2 = umin2(pb2, (__float_as_uint(c[2]) & MASK) | idx);
            pb3 = umin2(pb3, (__float_as_uint(c[3]) & MASK) | idx);
        }
        #pragma unroll
        for (int m = 1; m < 16; m <<= 1) {                  // min over 16 code-cols
            pb0 = umin2(pb0, (unsigned)__shfl_xor((int)pb0, m));
            pb1 = umin2(pb1, (unsigned)__shfl_xor((int)pb1, m));
            pb2 = umin2(pb2, (unsigned)__shfl_xor((int)pb2, m));
            pb3 = umin2(pb3, (unsigned)__shfl_xor((int)pb3, m));
        }
        if (col == 0) {                                     // rows kg*4 + reg
            const int rb = (ch << 4) + (kg << 2);
            kbuf[w][rb + 0] = pb0;
            kbuf[w][rb + 1] = pb1;
            kbuf[w][rb + 2] = pb2;
            kbuf[w][rb + 3] = pb3;
        }
    }
    __syncthreads();

    // ---- cross-wave argmin, loss partial, code selection ----
    float d = 0.0f;
    if (tid < 128) {
        const unsigned kk = umin2(umin2(kbuf[0][tid], kbuf[1][tid]),
                                  umin2(kbuf[2][tid], kbuf[3][tid]));
        bsel[tid] = (int)(kk & 1023u);
        // ||z-q||^2 = ||z||^2 + (s' - 4)
        d = __uint_as_float(kk & MASK) - 4.0f + zsqp[0][tid] + zsqp[1][tid];
    }
    #pragma unroll
    for (int m = 1; m < 64; m <<= 1) d += __shfl_xor(d, m);
    if (lane == 0) red[w] = d;
    __syncthreads();
    if (tid == 0) pblk[blockIdx.x] = red[0] + red[1] + red[2] + red[3];

    // ---- gather chosen codes + scatter to channel-major output ----
    {
        const int r = tid & 127;
        const int h = tid >> 7;
        const int n = row0 + r;
        const int base = ((n >> 12) << 18) + (n & 4095);
        const int code = bsel[r];
        const float4* erow = (const float4*)emb + (code << 4) + (h << 3);
        #pragma unroll
        for (int c4 = 0; c4 < 8; ++c4) {
            const float4 q = erow[c4];
            const int c = (h << 5) + (c4 << 2);
            out[base + ((c + 0) << 12)] = q.x;
            out[base + ((c + 1) << 12)] = q.y;
            out[base + ((c + 2) << 12)] = q.z;
            out[base + ((c + 3) << 12)] = q.w;
        }
    }
}

// Deterministic reduction of 512 per-block partials -> loss scalar.
__global__ void vq_loss2(const float* __restrict__ pblk,
                         float* __restrict__ out_loss) {
    const int tid = threadIdx.x;
    float d = pblk[tid] + pblk[tid + 256];
    #pragma unroll
    for (int m = 1; m < 64; m <<= 1) d += __shfl_xor(d, m);
    __shared__ float red[4];
    if ((tid & 63) == 0) red[tid >> 6] = d;
    __syncthreads();
    if (tid == 0)
        out_loss[0] = 1.25f * (red[0] + red[1] + red[2] + red[3]) * (1.0f / 4194304.0f);
}

extern "C" void kernel_launch(void* const* d_in, const int* in_sizes, int n_in,
                              void* d_out, int out_size, void* d_ws, size_t ws_size,
                              hipStream_t stream) {
    const float* z   = (const float*)d_in[0];
    const float* emb = (const float*)d_in[1];
    float* out  = (float*)d_out;
    float* pblk = (float*)d_ws;

    hipLaunchKernelGGL(vq_fused, dim3(512), dim3(256), 0, stream, z, emb, out, pblk);
    hipLaunchKernelGGL(vq_loss2, dim3(1), dim3(256), 0, stream, pblk, out + 4194304);
}